// Round 7
// baseline (120.278 us; speedup 1.0000x reference)
//
#include <hip/hip_runtime.h>

#define BB 512
#define NN 64
#define EE 64
#define DD 256
#define BND (BB * NN * DD)
#define NEGV (-9e15f)
#define SA 68

typedef __attribute__((ext_vector_type(8))) short s8v;
typedef __attribute__((ext_vector_type(4))) float f4v;
typedef __attribute__((ext_vector_type(8))) unsigned short u16x8;

__device__ __forceinline__ unsigned short f2bf(float f) {
    unsigned int x = __float_as_uint(f);
    x = x + 0x7fffu + ((x >> 16) & 1u);   // RNE
    return (unsigned short)(x >> 16);
}
__device__ __forceinline__ float bf2f(unsigned short u) {
    return __uint_as_float(((unsigned int)u) << 16);
}
__device__ __forceinline__ float lrelu(float v) { return v > 0.f ? v : 0.2f * v; }

// ws byte offsets
#define WS_PREP  0          // 2048 f32 (8KB)
#define WS_P3B   8192       // 256 f32
#define WS_WFRAG 12288      // 65536 bf16 (128KB)

// prep layout (floats): [0)p1a [256)p2a [512)p3a [768]c0a [1024)p1b [1280)p2b [1536)wp3b [1792]c0b
__global__ void prep_dots(const float* __restrict__ w2a, const float* __restrict__ w3a,
                          const float* __restrict__ aa, const float* __restrict__ a2a,
                          const float* __restrict__ wca,
                          const float* __restrict__ w2b, const float* __restrict__ w3b,
                          const float* __restrict__ ab, const float* __restrict__ a2b,
                          const float* __restrict__ wcb,
                          float* __restrict__ prep, float* __restrict__ p3b_ws) {
    const int t = threadIdx.x;
    const int blk = blockIdx.x;
    const int layer = blk >> 3;
    const int r0 = (blk & 7) * 32;
    __shared__ float vhi[256], v2lo[256], v2hi[256], red[256];
    const float* w2 = layer ? w2b : w2a;
    const float* w3 = layer ? w3b : w3a;
    const float* av = layer ? ab : aa;
    const float* a2 = layer ? a2b : a2a;
    vhi[t] = av[256 + t];
    v2lo[t] = a2[t];
    v2hi[t] = a2[256 + t];
    __syncthreads();
    const int row = r0 + (t >> 3), q = t & 7;
    const float* w2r = w2 + (size_t)row * DD + q * 32;
    const float* w3r = w3 + (size_t)row * DD + q * 32;
    float s1 = 0.f, s2 = 0.f, s3 = 0.f;
    #pragma unroll
    for (int c = 0; c < 8; c++) {
        float4 v = *(const float4*)&w2r[c * 4];
        float4 u = *(const float4*)&w3r[c * 4];
        float4 p1 = *(const float4*)&vhi[q * 32 + c * 4];
        float4 p2 = *(const float4*)&v2lo[q * 32 + c * 4];
        float4 p3 = *(const float4*)&v2hi[q * 32 + c * 4];
        s1 = fmaf(v.x, p1.x, fmaf(v.y, p1.y, fmaf(v.z, p1.z, fmaf(v.w, p1.w, s1))));
        s2 = fmaf(v.x, p2.x, fmaf(v.y, p2.y, fmaf(v.z, p2.z, fmaf(v.w, p2.w, s2))));
        s3 = fmaf(u.x, p3.x, fmaf(u.y, p3.y, fmaf(u.z, p3.z, fmaf(u.w, p3.w, s3))));
    }
    s1 += __shfl_xor(s1, 1); s1 += __shfl_xor(s1, 2); s1 += __shfl_xor(s1, 4);
    s2 += __shfl_xor(s2, 1); s2 += __shfl_xor(s2, 2); s2 += __shfl_xor(s2, 4);
    s3 += __shfl_xor(s3, 1); s3 += __shfl_xor(s3, 2); s3 += __shfl_xor(s3, 4);
    if (q == 0) {
        if (layer == 0) { prep[row] = s1; prep[256 + row] = s2; prep[512 + row] = s3; }
        else { prep[1024 + row] = s1; prep[1280 + row] = s2; p3b_ws[row] = s3; }
    }
    if ((blk & 7) == 0) {
        red[t] = layer ? (wcb[t] * ab[t]) : (wca[t] * aa[t]);
        __syncthreads();
        for (int o = 128; o > 0; o >>= 1) { if (t < o) red[t] += red[t + o]; __syncthreads(); }
        if (t == 0) prep[layer ? 1792 : 768] = red[0];
    }
}

// blocks 0..7: wp3b = wtr @ p3b ; blocks 8..39: pack g2_w into MFMA B-fragments
__global__ void prep2_pack(const float* __restrict__ wtr, const float* __restrict__ p3b_ws,
                           float* __restrict__ prep, unsigned short* __restrict__ wfrag) {
    const int t = threadIdx.x, blk = blockIdx.x;
    __shared__ float p3[256];
    if (blk < 8) {
        p3[t] = p3b_ws[t];
        __syncthreads();
        const int row = blk * 32 + (t >> 3), q = t & 7;
        const float* wr = wtr + (size_t)row * DD + q * 32;
        float s = 0.f;
        #pragma unroll
        for (int c = 0; c < 8; c++) {
            float4 v = *(const float4*)&wr[c * 4];
            float4 p = *(const float4*)&p3[q * 32 + c * 4];
            s = fmaf(v.x, p.x, fmaf(v.y, p.y, fmaf(v.z, p.z, fmaf(v.w, p.w, s))));
        }
        s += __shfl_xor(s, 1); s += __shfl_xor(s, 2); s += __shfl_xor(s, 4);
        if (q == 0) prep[1536 + row] = s;
    } else {
        int gid = (blk - 8) * 256 + t;      // 0..8191
        int l = gid & 63, frag = gid >> 6;
        int kc = frag >> 4, nt = frag & 15;
        int kb = kc * 32 + (l >> 4) * 8;
        int n = nt * 16 + (l & 15);
        u16x8 u;
        #pragma unroll
        for (int j = 0; j < 8; j++) u[j] = f2bf(wtr[(size_t)(kb + j) * DD + n]);
        *(u16x8*)(wfrag + (size_t)gid * 8) = u;
    }
}

// Two blocks per batch (h = feature half). Each duplicates the softmax->M chain
// (all in LDS), then GEMM1/GEMM2/epilogue/nodes2 for its 128-col half.
__launch_bounds__(512, 8)
__global__ void mega(const int* __restrict__ inputs, const int* __restrict__ HT,
                     const float* __restrict__ emb_w, const float* __restrict__ emb2_w,
                     const float* __restrict__ prep, const unsigned short* __restrict__ wfrag,
                     float* __restrict__ out) {
    __shared__ unsigned short YTC[128 * SA];   // C1'^T (64x68) until P9; YT half after
    __shared__ unsigned short bufE[64 * SA];   // attE1 -> attE2 -> M
    __shared__ unsigned short bufN[64 * SA];   // attN1 -> attN2 -> C2
    __shared__ float dvs[384];
    __shared__ float uu[64];
    __shared__ float db2[192];
    __shared__ unsigned long long mE[64], mN[64];
    __shared__ int idxs[64];

    const int bh = blockIdx.x;
    const int b = bh >> 1;
    const int h = bh & 1;
    const int t = threadIdx.x;
    const int lane = t & 63;
    const int w8 = t >> 6;                 // wave 0..7
    const int l15 = lane & 15, lh = lane >> 4;

    if (t < 64) idxs[t] = inputs[b * 64 + t];
    __syncthreads();

    // ---- P1: dv-dots (f32 from global) ; HT masks ; nodes2 half-copy ----
    {
        const int rw = t >> 3, q8 = t & 7;
        const float* src = emb_w + (size_t)idxs[rw] * DD + q8 * 32;
        float a6[6] = {0.f, 0.f, 0.f, 0.f, 0.f, 0.f};
        const int poff[6] = {0, 256, 512, 1024, 1280, 1536};
        #pragma unroll
        for (int c = 0; c < 8; c++) {
            float4 v = *(const float4*)&src[c * 4];
            #pragma unroll
            for (int j = 0; j < 6; j++) {
                float4 p = *(const float4*)&prep[poff[j] + q8 * 32 + c * 4];
                a6[j] = fmaf(v.x, p.x, fmaf(v.y, p.y, fmaf(v.z, p.z, fmaf(v.w, p.w, a6[j]))));
            }
        }
        #pragma unroll
        for (int j = 0; j < 6; j++) {
            a6[j] += __shfl_xor(a6[j], 1);
            a6[j] += __shfl_xor(a6[j], 2);
            a6[j] += __shfl_xor(a6[j], 4);
        }
        if (q8 == 0) {
            #pragma unroll
            for (int j = 0; j < 6; j++) dvs[j * 64 + rw] = a6[j];
        }
    }
    #pragma unroll
    for (int i = 0; i < 8; i++) {
        int e = w8 * 8 + i;
        int hx = HT[((size_t)b * EE + e) * NN + lane];
        unsigned long long m = __ballot(hx > 0);
        if (lane == 0) mE[e] = m;
    }
    for (int i = t; i < 64 * 32; i += 512) {
        int n = i >> 5, c = i & 31;
        float4 v = ((const float4*)(emb2_w + (size_t)idxs[n] * DD + h * 128))[c];
        ((float4*)(out + (size_t)2 * BND + (size_t)(b * 64 + n) * DD + h * 128))[c] = v;
    }
    __syncthreads();

    // ---- P2: mN ; attE1 softmax + u1 -> bufE, uu ----
    if (t < 64) {
        unsigned long long acc = 0ull;
        for (int e = 0; e < 64; e++) acc |= ((mE[e] >> t) & 1ull) << e;
        mN[t] = acc;
    }
    {
        float s1n = lrelu(prep[768] + dvs[lane]);
        float d2 = dvs[128 + lane];
        for (int i = 0; i < 8; i++) {
            int e = w8 * 8 + i;
            bool mk = (mE[e] >> lane) & 1ull;
            float v = mk ? s1n : NEGV;
            float mx = v;
            #pragma unroll
            for (int o = 32; o > 0; o >>= 1) mx = fmaxf(mx, __shfl_xor(mx, o));
            float p = __expf(v - mx);
            float s = p, sd = p * d2;
            #pragma unroll
            for (int o = 32; o > 0; o >>= 1) { s += __shfl_xor(s, o); sd += __shfl_xor(sd, o); }
            bufE[lane * SA + e] = f2bf(p / s);
            if (lane == 0) uu[e] = sd / s;
        }
    }
    __syncthreads();

    // ---- P3: attN1 -> bufN ----
    {
        float ul = uu[lane];
        for (int i = 0; i < 8; i++) {
            int n = w8 * 8 + i;
            float sv = lrelu(dvs[64 + n] + ul);
            bool mk = (mN[n] >> lane) & 1ull;
            float v = mk ? sv : NEGV;
            float mx = v;
            #pragma unroll
            for (int o = 32; o > 0; o >>= 1) mx = fmaxf(mx, __shfl_xor(mx, o));
            float p = __expf(v - mx), s = p;
            #pragma unroll
            for (int o = 32; o > 0; o >>= 1) s += __shfl_xor(s, o);
            bufN[n * SA + lane] = f2bf(p / s);
        }
    }
    __syncthreads();

    const int wr = (w8 & 3) * 16;
    const int wc = (w8 >> 2) * 32;
    const int row0 = wr + lh * 4;
    const int ct4 = (w8 >> 2) * 4;

    // ---- P4: C1' = attN1 @ attE1 + I -> C1T (in YTC, col-major) ----
    {
        f4v a0 = {0.f,0.f,0.f,0.f}, a1 = {0.f,0.f,0.f,0.f};
        #pragma unroll
        for (int kc = 0; kc < 2; kc++) {
            s8v a  = *(const s8v*)&bufN[(wr + l15) * SA + kc * 32 + lh * 8];
            s8v b0 = *(const s8v*)&bufE[(wc + l15) * SA + kc * 32 + lh * 8];
            s8v b1 = *(const s8v*)&bufE[(wc + 16 + l15) * SA + kc * 32 + lh * 8];
            a0 = __builtin_amdgcn_mfma_f32_16x16x32_bf16(a, b0, a0, 0, 0, 0);
            a1 = __builtin_amdgcn_mfma_f32_16x16x32_bf16(a, b1, a1, 0, 0, 0);
        }
        int col0 = wc + l15, col1 = wc + 16 + l15;
        ushort4 u0, u1;
        #pragma unroll
        for (int rg = 0; rg < 4; rg++) {
            ((unsigned short*)&u0)[rg] = f2bf(a0[rg] + ((row0 + rg) == col0 ? 1.f : 0.f));
            ((unsigned short*)&u1)[rg] = f2bf(a1[rg] + ((row0 + rg) == col1 ? 1.f : 0.f));
        }
        *(ushort4*)&YTC[col0 * SA + row0] = u0;
        *(ushort4*)&YTC[col1 * SA + row0] = u1;
    }
    __syncthreads();

    // ---- P5: db2[j] = C1' @ dvs[3+j] (column reads of C1T) ----
    {
        const int n8 = t >> 3, q8 = t & 7;
        float s0 = 0.f, s1 = 0.f, s2 = 0.f;
        #pragma unroll
        for (int jj = 0; jj < 8; jj++) {
            int j = q8 * 8 + jj;
            float c = bf2f(YTC[j * SA + n8]);
            s0 = fmaf(c, dvs[192 + j], s0);
            s1 = fmaf(c, dvs[256 + j], s1);
            s2 = fmaf(c, dvs[320 + j], s2);
        }
        s0 += __shfl_xor(s0, 1); s0 += __shfl_xor(s0, 2); s0 += __shfl_xor(s0, 4);
        s1 += __shfl_xor(s1, 1); s1 += __shfl_xor(s1, 2); s1 += __shfl_xor(s1, 4);
        s2 += __shfl_xor(s2, 1); s2 += __shfl_xor(s2, 2); s2 += __shfl_xor(s2, 4);
        if (q8 == 0) { db2[n8] = s0; db2[64 + n8] = s1; db2[128 + n8] = s2; }
    }
    __syncthreads();

    // ---- P6: attE2 softmax + u2 -> bufE, uu ----
    {
        float s1n = lrelu(prep[1792] + db2[lane]);
        float d2 = db2[128 + lane];
        for (int i = 0; i < 8; i++) {
            int e = w8 * 8 + i;
            bool mk = (mE[e] >> lane) & 1ull;
            float v = mk ? s1n : NEGV;
            float mx = v;
            #pragma unroll
            for (int o = 32; o > 0; o >>= 1) mx = fmaxf(mx, __shfl_xor(mx, o));
            float p = __expf(v - mx);
            float s = p, sd = p * d2;
            #pragma unroll
            for (int o = 32; o > 0; o >>= 1) { s += __shfl_xor(s, o); sd += __shfl_xor(sd, o); }
            bufE[lane * SA + e] = f2bf(p / s);
            if (lane == 0) uu[e] = sd / s;
        }
    }
    __syncthreads();

    // ---- P7: attN2 -> bufN ----
    {
        float ul = uu[lane];
        for (int i = 0; i < 8; i++) {
            int n = w8 * 8 + i;
            float sv = lrelu(db2[64 + n] + ul);
            bool mk = (mN[n] >> lane) & 1ull;
            float v = mk ? sv : NEGV;
            float mx = v;
            #pragma unroll
            for (int o = 32; o > 0; o >>= 1) mx = fmaxf(mx, __shfl_xor(mx, o));
            float p = __expf(v - mx), s = p;
            #pragma unroll
            for (int o = 32; o > 0; o >>= 1) s += __shfl_xor(s, o);
            bufN[n * SA + lane] = f2bf(p / s);
        }
    }
    __syncthreads();

    // ---- P8: C2 = attN2 @ attE2 -> regs ; barrier ; -> bufN ----
    {
        f4v a0 = {0.f,0.f,0.f,0.f}, a1 = {0.f,0.f,0.f,0.f};
        #pragma unroll
        for (int kc = 0; kc < 2; kc++) {
            s8v a  = *(const s8v*)&bufN[(wr + l15) * SA + kc * 32 + lh * 8];
            s8v b0 = *(const s8v*)&bufE[(wc + l15) * SA + kc * 32 + lh * 8];
            s8v b1 = *(const s8v*)&bufE[(wc + 16 + l15) * SA + kc * 32 + lh * 8];
            a0 = __builtin_amdgcn_mfma_f32_16x16x32_bf16(a, b0, a0, 0, 0, 0);
            a1 = __builtin_amdgcn_mfma_f32_16x16x32_bf16(a, b1, a1, 0, 0, 0);
        }
        __syncthreads();
        #pragma unroll
        for (int rg = 0; rg < 4; rg++) {
            bufN[(row0 + rg) * SA + wc + l15] = f2bf(a0[rg]);
            bufN[(row0 + rg) * SA + wc + 16 + l15] = f2bf(a1[rg]);
        }
    }
    __syncthreads();

    // ---- P9: M = C2 @ C1' -> bufE ----
    {
        f4v a0 = {0.f,0.f,0.f,0.f}, a1 = {0.f,0.f,0.f,0.f};
        #pragma unroll
        for (int kc = 0; kc < 2; kc++) {
            s8v a  = *(const s8v*)&bufN[(wr + l15) * SA + kc * 32 + lh * 8];
            s8v b0 = *(const s8v*)&YTC[(wc + l15) * SA + kc * 32 + lh * 8];
            s8v b1 = *(const s8v*)&YTC[(wc + 16 + l15) * SA + kc * 32 + lh * 8];
            a0 = __builtin_amdgcn_mfma_f32_16x16x32_bf16(a, b0, a0, 0, 0, 0);
            a1 = __builtin_amdgcn_mfma_f32_16x16x32_bf16(a, b1, a1, 0, 0, 0);
        }
        #pragma unroll
        for (int rg = 0; rg < 4; rg++) {
            bufE[(row0 + rg) * SA + wc + l15] = f2bf(a0[rg]);
            bufE[(row0 + rg) * SA + wc + 16 + l15] = f2bf(a1[rg]);
        }
    }
    __syncthreads();   // C1T reads + M writes complete

    // ---- P10: GEMM1 (half h): Y = x0 @ w, A-frags straight from global ----
    {
        f4v acc[4];
        #pragma unroll
        for (int nt = 0; nt < 4; nt++) acc[nt] = (f4v){0.f, 0.f, 0.f, 0.f};
        const s8v* wf = (const s8v*)wfrag;
        const float* arow_p = emb_w + (size_t)idxs[wr + l15] * DD + lh * 8;
        #pragma unroll
        for (int kc = 0; kc < 8; kc++) {
            float4 v0 = *(const float4*)(arow_p + kc * 32);
            float4 v1 = *(const float4*)(arow_p + kc * 32 + 4);
            u16x8 au;
            au[0] = f2bf(v0.x); au[1] = f2bf(v0.y); au[2] = f2bf(v0.z); au[3] = f2bf(v0.w);
            au[4] = f2bf(v1.x); au[5] = f2bf(v1.y); au[6] = f2bf(v1.z); au[7] = f2bf(v1.w);
            s8v a = (s8v)au;
            #pragma unroll
            for (int nt = 0; nt < 4; nt++) {
                s8v bv = wf[(size_t)(kc * 16 + h * 8 + ct4 + nt) * 64 + lane];
                acc[nt] = __builtin_amdgcn_mfma_f32_16x16x32_bf16(a, bv, acc[nt], 0, 0, 0);
            }
        }
        #pragma unroll
        for (int nt = 0; nt < 4; nt++) {
            int fl = (ct4 + nt) * 16 + l15;     // 0..127 local feature
            ushort4 u;
            u.x = f2bf(acc[nt][0]); u.y = f2bf(acc[nt][1]);
            u.z = f2bf(acc[nt][2]); u.w = f2bf(acc[nt][3]);
            *(ushort4*)&YTC[fl * SA + row0] = u;
        }
    }
    __syncthreads();

    // ---- P11: out = M @ Y + x0 (half h) ----
    {
        f4v acc2[4];
        #pragma unroll
        for (int nt = 0; nt < 4; nt++) acc2[nt] = (f4v){0.f, 0.f, 0.f, 0.f};
        #pragma unroll
        for (int kc = 0; kc < 2; kc++) {
            s8v a = *(const s8v*)&bufE[(wr + l15) * SA + kc * 32 + lh * 8];
            #pragma unroll
            for (int nt = 0; nt < 4; nt++) {
                s8v bv = *(const s8v*)&YTC[((ct4 + nt) * 16 + l15) * SA + kc * 32 + lh * 8];
                acc2[nt] = __builtin_amdgcn_mfma_f32_16x16x32_bf16(a, bv, acc2[nt], 0, 0, 0);
            }
        }
        #pragma unroll
        for (int nt = 0; nt < 4; nt++) {
            #pragma unroll
            for (int rg = 0; rg < 4; rg++) {
                int row = row0 + rg;
                int colg = h * 128 + (ct4 + nt) * 16 + l15;
                float r = emb_w[(size_t)idxs[row] * DD + colg];
                float v = acc2[nt][rg] + r;
                size_t o = (size_t)(b * 64 + row) * DD + colg;
                out[o] = v;
                out[BND + o] = v;
            }
        }
    }
}

extern "C" void kernel_launch(void* const* d_in, const int* in_sizes, int n_in,
                              void* d_out, int out_size, void* d_ws, size_t ws_size,
                              hipStream_t stream) {
    const int* inputs = (const int*)d_in[0];
    const int* HT = (const int*)d_in[1];
    const float* emb_w  = (const float*)d_in[4];
    const float* emb2_w = (const float*)d_in[5];
    const float* g1_w2 = (const float*)d_in[6];
    const float* g1_w3 = (const float*)d_in[7];
    const float* g1_a  = (const float*)d_in[8];
    const float* g1_a2 = (const float*)d_in[9];
    const float* g1_wc = (const float*)d_in[10];
    const float* g2_w  = (const float*)d_in[11];
    const float* g2_w2 = (const float*)d_in[12];
    const float* g2_w3 = (const float*)d_in[13];
    const float* g2_a  = (const float*)d_in[14];
    const float* g2_a2 = (const float*)d_in[15];
    const float* g2_wc = (const float*)d_in[16];

    float* out = (float*)d_out;
    float* prep = (float*)((char*)d_ws + WS_PREP);
    float* p3b_ws = (float*)((char*)d_ws + WS_P3B);
    unsigned short* wfrag = (unsigned short*)((char*)d_ws + WS_WFRAG);

    prep_dots<<<16, 256, 0, stream>>>(g1_w2, g1_w3, g1_a, g1_a2, g1_wc,
                                      g2_w2, g2_w3, g2_a, g2_a2, g2_wc,
                                      prep, p3b_ws);
    prep2_pack<<<40, 256, 0, stream>>>(g2_w, p3b_ws, prep, wfrag);
    mega<<<2 * BB, 512, 0, stream>>>(inputs, HT, emb_w, emb2_w, prep, wfrag, out);
}

// Round 8
// 88.379 us; speedup vs baseline: 1.3609x; 1.3609x over previous
//
#include <hip/hip_runtime.h>

#define BB 512
#define NN 64
#define EE 64
#define DD 256
#define BND (BB * NN * DD)
#define SA 68

typedef __attribute__((ext_vector_type(8))) short s8v;
typedef __attribute__((ext_vector_type(4))) float f4v;
typedef __attribute__((ext_vector_type(8))) unsigned short u16x8;

__device__ __forceinline__ unsigned short f2bf(float f) {
    unsigned int x = __float_as_uint(f);
    x = x + 0x7fffu + ((x >> 16) & 1u);   // RNE
    return (unsigned short)(x >> 16);
}
__device__ __forceinline__ float lrelu(float v) { return v > 0.f ? v : 0.2f * v; }

// ws byte offsets
#define WS_PREP  0          // 2048 f32 (8KB)
#define WS_P3B   8192       // 256 f32
#define WS_WFRAG 12288      // 65536 bf16 (128KB)

// prep layout (floats): [0)p1a [256)p2a [512)p3a [768]c0a [1024)p1b [1280)p2b [1536)wp3b [1792]c0b
__global__ void prep_dots(const float* __restrict__ w2a, const float* __restrict__ w3a,
                          const float* __restrict__ aa, const float* __restrict__ a2a,
                          const float* __restrict__ wca,
                          const float* __restrict__ w2b, const float* __restrict__ w3b,
                          const float* __restrict__ ab, const float* __restrict__ a2b,
                          const float* __restrict__ wcb,
                          float* __restrict__ prep, float* __restrict__ p3b_ws) {
    const int t = threadIdx.x;
    const int blk = blockIdx.x;
    const int layer = blk >> 3;
    const int r0 = (blk & 7) * 32;
    __shared__ float vhi[256], v2lo[256], v2hi[256], red[256];
    const float* w2 = layer ? w2b : w2a;
    const float* w3 = layer ? w3b : w3a;
    const float* av = layer ? ab : aa;
    const float* a2 = layer ? a2b : a2a;
    vhi[t] = av[256 + t];
    v2lo[t] = a2[t];
    v2hi[t] = a2[256 + t];
    __syncthreads();
    const int row = r0 + (t >> 3), q = t & 7;
    const float* w2r = w2 + (size_t)row * DD + q * 32;
    const float* w3r = w3 + (size_t)row * DD + q * 32;
    float s1 = 0.f, s2 = 0.f, s3 = 0.f;
    #pragma unroll
    for (int c = 0; c < 8; c++) {
        float4 v = *(const float4*)&w2r[c * 4];
        float4 u = *(const float4*)&w3r[c * 4];
        float4 p1 = *(const float4*)&vhi[q * 32 + c * 4];
        float4 p2 = *(const float4*)&v2lo[q * 32 + c * 4];
        float4 p3 = *(const float4*)&v2hi[q * 32 + c * 4];
        s1 = fmaf(v.x, p1.x, fmaf(v.y, p1.y, fmaf(v.z, p1.z, fmaf(v.w, p1.w, s1))));
        s2 = fmaf(v.x, p2.x, fmaf(v.y, p2.y, fmaf(v.z, p2.z, fmaf(v.w, p2.w, s2))));
        s3 = fmaf(u.x, p3.x, fmaf(u.y, p3.y, fmaf(u.z, p3.z, fmaf(u.w, p3.w, s3))));
    }
    s1 += __shfl_xor(s1, 1); s1 += __shfl_xor(s1, 2); s1 += __shfl_xor(s1, 4);
    s2 += __shfl_xor(s2, 1); s2 += __shfl_xor(s2, 2); s2 += __shfl_xor(s2, 4);
    s3 += __shfl_xor(s3, 1); s3 += __shfl_xor(s3, 2); s3 += __shfl_xor(s3, 4);
    if (q == 0) {
        if (layer == 0) { prep[row] = s1; prep[256 + row] = s2; prep[512 + row] = s3; }
        else { prep[1024 + row] = s1; prep[1280 + row] = s2; p3b_ws[row] = s3; }
    }
    if ((blk & 7) == 0) {
        red[t] = layer ? (wcb[t] * ab[t]) : (wca[t] * aa[t]);
        __syncthreads();
        for (int o = 128; o > 0; o >>= 1) { if (t < o) red[t] += red[t + o]; __syncthreads(); }
        if (t == 0) prep[layer ? 1792 : 768] = red[0];
    }
}

// blocks 0..7: wp3b = wtr @ p3b ; blocks 8..39: pack g2_w into MFMA B-fragments
__global__ void prep2_pack(const float* __restrict__ wtr, const float* __restrict__ p3b_ws,
                           float* __restrict__ prep, unsigned short* __restrict__ wfrag) {
    const int t = threadIdx.x, blk = blockIdx.x;
    __shared__ float p3[256];
    if (blk < 8) {
        p3[t] = p3b_ws[t];
        __syncthreads();
        const int row = blk * 32 + (t >> 3), q = t & 7;
        const float* wr = wtr + (size_t)row * DD + q * 32;
        float s = 0.f;
        #pragma unroll
        for (int c = 0; c < 8; c++) {
            float4 v = *(const float4*)&wr[c * 4];
            float4 p = *(const float4*)&p3[q * 32 + c * 4];
            s = fmaf(v.x, p.x, fmaf(v.y, p.y, fmaf(v.z, p.z, fmaf(v.w, p.w, s))));
        }
        s += __shfl_xor(s, 1); s += __shfl_xor(s, 2); s += __shfl_xor(s, 4);
        if (q == 0) prep[1536 + row] = s;
    } else {
        int gid = (blk - 8) * 256 + t;      // 0..8191
        int l = gid & 63, frag = gid >> 6;
        int kc = frag >> 4, nt = frag & 15;
        int kb = kc * 32 + (l >> 4) * 8;
        int n = nt * 16 + (l & 15);
        u16x8 u;
        #pragma unroll
        for (int j = 0; j < 8; j++) u[j] = f2bf(wtr[(size_t)(kb + j) * DD + n]);
        *(u16x8*)(wfrag + (size_t)gid * 8) = u;
    }
}

// One block per batch. Global-shift softmax (no per-row max), factored normalization,
// MFMA for all matrix work. Unnormalized P matrices; col-scale 1/De at write,
// row-scale 1/Dn in MFMA epilogue.
__launch_bounds__(512, 4)
__global__ void mega(const int* __restrict__ inputs, const int* __restrict__ HT,
                     const float* __restrict__ emb_w, const float* __restrict__ emb2_w,
                     const float* __restrict__ prep, const unsigned short* __restrict__ wfrag,
                     float* __restrict__ out) {
    __shared__ unsigned short bufA[256 * SA];   // x0bf [64][264] -> YT [256][68]
    __shared__ unsigned short bufE[64 * SA];    // Pe1 -> Pe2 -> M
    __shared__ unsigned short bufN[64 * SA];    // Pn1' -> Pn2'
    __shared__ unsigned short bufT[64 * SA];    // C1'^T
    __shared__ unsigned short bufC[64 * SA];    // C2 row-major
    __shared__ float dvs[384];
    __shared__ float db2[192];
    __shared__ float u1f[64], invdef[64], invdnf[64];
    __shared__ unsigned long long mE[64], mN[64];
    __shared__ int idxs[64];

    const int b = blockIdx.x;
    const int t = threadIdx.x;
    const int lane = t & 63;
    const int w8 = t >> 6;
    const int l15 = lane & 15, lh = lane >> 4;

    if (t < 64) idxs[t] = inputs[b * 64 + t];
    __syncthreads();

    // ---- P1: stage x0 bf16 + 6 dv-dots (f32) ; mE ballots ; nodes2 copy ----
    {
        const int rw = t >> 3, q8 = t & 7;
        const float* src = emb_w + (size_t)idxs[rw] * DD + q8 * 32;
        float a6[6] = {0.f, 0.f, 0.f, 0.f, 0.f, 0.f};
        const int poff[6] = {0, 256, 512, 1024, 1280, 1536};
        #pragma unroll
        for (int c = 0; c < 8; c++) {
            float4 v = *(const float4*)&src[c * 4];
            ushort4 u;
            u.x = f2bf(v.x); u.y = f2bf(v.y); u.z = f2bf(v.z); u.w = f2bf(v.w);
            *(ushort4*)&bufA[rw * 264 + q8 * 32 + c * 4] = u;
            #pragma unroll
            for (int j = 0; j < 6; j++) {
                float4 p = *(const float4*)&prep[poff[j] + q8 * 32 + c * 4];
                a6[j] = fmaf(v.x, p.x, fmaf(v.y, p.y, fmaf(v.z, p.z, fmaf(v.w, p.w, a6[j]))));
            }
        }
        #pragma unroll
        for (int j = 0; j < 6; j++) {
            a6[j] += __shfl_xor(a6[j], 1);
            a6[j] += __shfl_xor(a6[j], 2);
            a6[j] += __shfl_xor(a6[j], 4);
        }
        if (q8 == 0) {
            #pragma unroll
            for (int j = 0; j < 6; j++) dvs[j * 64 + rw] = a6[j];
        }
    }
    #pragma unroll
    for (int i = 0; i < 8; i++) {
        int e = w8 * 8 + i;
        int hx = HT[((size_t)b * EE + e) * NN + lane];
        unsigned long long m = __ballot(hx > 0);
        if (lane == 0) mE[e] = m;
    }
    for (int i = t; i < 64 * 64; i += 512) {
        int n = i >> 6, c = i & 63;
        float4 v = ((const float4*)(emb2_w + (size_t)idxs[n] * DD))[c];
        ((float4*)(out + (size_t)2 * BND + (size_t)(b * 64 + n) * DD))[c] = v;
    }
    __syncthreads();

    float gt2;   // max over t2 (all waves hold same value)

    // ---- P2: mN ; Pe1 (unnorm, global shift) + De1,We1 per row -> u1f, invdef ----
    if (t < 64) {
        unsigned long long acc = 0ull;
        for (int e = 0; e < 64; e++) acc |= ((mE[e] >> t) & 1ull) << e;
        mN[t] = acc;
    }
    {
        float s1l = lrelu(prep[768] + dvs[lane]);
        float g1 = s1l;
        #pragma unroll
        for (int o = 32; o > 0; o >>= 1) g1 = fmaxf(g1, __shfl_xor(g1, o));
        float E1 = __expf(s1l - g1);
        float t2l = dvs[64 + lane];
        gt2 = t2l;
        #pragma unroll
        for (int o = 32; o > 0; o >>= 1) gt2 = fmaxf(gt2, __shfl_xor(gt2, o));
        float d2 = dvs[128 + lane];
        for (int i = 0; i < 8; i++) {
            int e = w8 * 8 + i;
            unsigned long long me = mE[e];
            float pe = (me == 0ull) ? 1.f : (((me >> lane) & 1ull) ? E1 : 0.f);
            bufE[lane * SA + e] = f2bf(pe);
            float s = pe, sd = pe * d2;
            #pragma unroll
            for (int o = 32; o > 0; o >>= 1) { s += __shfl_xor(s, o); sd += __shfl_xor(sd, o); }
            if (lane == 0) { u1f[e] = sd / s; invdef[e] = 1.f / s; }
        }
    }
    __syncthreads();

    // ---- P3: Pn1' = Pn1/De1 (global shift) ; Dn1 row-sums -> invdnf ----
    {
        float um = u1f[lane];
        #pragma unroll
        for (int o = 32; o > 0; o >>= 1) um = fmaxf(um, __shfl_xor(um, o));
        float M1 = lrelu(gt2 + um);
        float ul = u1f[lane];
        float ide = invdef[lane];
        for (int i = 0; i < 8; i++) {
            int n = w8 * 8 + i;
            unsigned long long mn = mN[n];
            float t2n = dvs[64 + n];
            float pr = (mn == 0ull) ? 1.f
                     : (((mn >> lane) & 1ull) ? __expf(lrelu(t2n + ul) - M1) : 0.f);
            float dn = pr;
            #pragma unroll
            for (int o = 32; o > 0; o >>= 1) dn += __shfl_xor(dn, o);
            bufN[n * SA + lane] = f2bf(pr * ide);
            if (lane == 0) invdnf[n] = 1.f / dn;
        }
    }
    __syncthreads();

    const int wr = (w8 & 3) * 16;
    const int wc = (w8 >> 2) * 32;
    const int row0 = wr + lh * 4;

    // ---- P4: C1' = Dn1^-1 (Pn1'@Pe1) + I -> bufT (col-major) ----
    {
        f4v a0 = {0.f,0.f,0.f,0.f}, a1 = {0.f,0.f,0.f,0.f};
        #pragma unroll
        for (int kc = 0; kc < 2; kc++) {
            s8v a  = *(const s8v*)&bufN[(wr + l15) * SA + kc * 32 + lh * 8];
            s8v b0 = *(const s8v*)&bufE[(wc + l15) * SA + kc * 32 + lh * 8];
            s8v b1 = *(const s8v*)&bufE[(wc + 16 + l15) * SA + kc * 32 + lh * 8];
            a0 = __builtin_amdgcn_mfma_f32_16x16x32_bf16(a, b0, a0, 0, 0, 0);
            a1 = __builtin_amdgcn_mfma_f32_16x16x32_bf16(a, b1, a1, 0, 0, 0);
        }
        int col0 = wc + l15, col1 = wc + 16 + l15;
        ushort4 u0, u1;
        #pragma unroll
        for (int rg = 0; rg < 4; rg++) {
            float idn = invdnf[row0 + rg];
            ((unsigned short*)&u0)[rg] = f2bf(a0[rg] * idn + ((row0 + rg) == col0 ? 1.f : 0.f));
            ((unsigned short*)&u1)[rg] = f2bf(a1[rg] * idn + ((row0 + rg) == col1 ? 1.f : 0.f));
        }
        *(ushort4*)&bufT[col0 * SA + row0] = u0;
        *(ushort4*)&bufT[col1 * SA + row0] = u1;
    }
    __syncthreads();

    // ---- P5: db2[j] = C1' @ dvs[3+j] via MFMA (waves 4..7) ----
    if (w8 >= 4) {
        const int ntile = (w8 - 4) * 16;
        f4v acc = {0.f, 0.f, 0.f, 0.f};
        #pragma unroll
        for (int kc = 0; kc < 2; kc++) {
            u16x8 au;
            #pragma unroll
            for (int jj = 0; jj < 8; jj++) {
                int k = kc * 32 + lh * 8 + jj;
                au[jj] = (l15 < 3) ? f2bf(dvs[192 + l15 * 64 + k]) : (unsigned short)0;
            }
            s8v bv = *(const s8v*)&bufT[(ntile + l15) * SA + kc * 32 + lh * 8];
            acc = __builtin_amdgcn_mfma_f32_16x16x32_bf16((s8v)au, bv, acc, 0, 0, 0);
        }
        if (lh == 0) {
            #pragma unroll
            for (int rg = 0; rg < 3; rg++) db2[rg * 64 + ntile + l15] = acc[rg];
        }
    }
    __syncthreads();

    float gdb1;

    // ---- P6: Pe2 + De2,We2 -> u1f, invdef (reuse) ----
    {
        float s2l = lrelu(prep[1792] + db2[lane]);
        float g2 = s2l;
        #pragma unroll
        for (int o = 32; o > 0; o >>= 1) g2 = fmaxf(g2, __shfl_xor(g2, o));
        float E2 = __expf(s2l - g2);
        float d1l = db2[64 + lane];
        gdb1 = d1l;
        #pragma unroll
        for (int o = 32; o > 0; o >>= 1) gdb1 = fmaxf(gdb1, __shfl_xor(gdb1, o));
        float d2 = db2[128 + lane];
        for (int i = 0; i < 8; i++) {
            int e = w8 * 8 + i;
            unsigned long long me = mE[e];
            float pe = (me == 0ull) ? 1.f : (((me >> lane) & 1ull) ? E2 : 0.f);
            bufE[lane * SA + e] = f2bf(pe);
            float s = pe, sd = pe * d2;
            #pragma unroll
            for (int o = 32; o > 0; o >>= 1) { s += __shfl_xor(s, o); sd += __shfl_xor(sd, o); }
            if (lane == 0) { u1f[e] = sd / s; invdef[e] = 1.f / s; }
        }
    }
    __syncthreads();

    // ---- P7: Pn2' + Dn2 -> bufN, invdnf (reuse) ----
    {
        float um = u1f[lane];
        #pragma unroll
        for (int o = 32; o > 0; o >>= 1) um = fmaxf(um, __shfl_xor(um, o));
        float M2 = lrelu(gdb1 + um);
        float ul = u1f[lane];
        float ide = invdef[lane];
        for (int i = 0; i < 8; i++) {
            int n = w8 * 8 + i;
            unsigned long long mn = mN[n];
            float d1n = db2[64 + n];
            float pr = (mn == 0ull) ? 1.f
                     : (((mn >> lane) & 1ull) ? __expf(lrelu(d1n + ul) - M2) : 0.f);
            float dn = pr;
            #pragma unroll
            for (int o = 32; o > 0; o >>= 1) dn += __shfl_xor(dn, o);
            bufN[n * SA + lane] = f2bf(pr * ide);
            if (lane == 0) invdnf[n] = 1.f / dn;
        }
    }
    __syncthreads();

    // ---- P8: C2 = Dn2^-1 (Pn2'@Pe2) -> bufC (row-major) ----
    {
        f4v a0 = {0.f,0.f,0.f,0.f}, a1 = {0.f,0.f,0.f,0.f};
        #pragma unroll
        for (int kc = 0; kc < 2; kc++) {
            s8v a  = *(const s8v*)&bufN[(wr + l15) * SA + kc * 32 + lh * 8];
            s8v b0 = *(const s8v*)&bufE[(wc + l15) * SA + kc * 32 + lh * 8];
            s8v b1 = *(const s8v*)&bufE[(wc + 16 + l15) * SA + kc * 32 + lh * 8];
            a0 = __builtin_amdgcn_mfma_f32_16x16x32_bf16(a, b0, a0, 0, 0, 0);
            a1 = __builtin_amdgcn_mfma_f32_16x16x32_bf16(a, b1, a1, 0, 0, 0);
        }
        #pragma unroll
        for (int rg = 0; rg < 4; rg++) {
            float idn = invdnf[row0 + rg];
            bufC[(row0 + rg) * SA + wc + l15] = f2bf(a0[rg] * idn);
            bufC[(row0 + rg) * SA + wc + 16 + l15] = f2bf(a1[rg] * idn);
        }
    }
    __syncthreads();

    // ---- P9: M = C2 @ C1' -> bufE (row-major; Pe2 dead) ----
    {
        f4v a0 = {0.f,0.f,0.f,0.f}, a1 = {0.f,0.f,0.f,0.f};
        #pragma unroll
        for (int kc = 0; kc < 2; kc++) {
            s8v a  = *(const s8v*)&bufC[(wr + l15) * SA + kc * 32 + lh * 8];
            s8v b0 = *(const s8v*)&bufT[(wc + l15) * SA + kc * 32 + lh * 8];
            s8v b1 = *(const s8v*)&bufT[(wc + 16 + l15) * SA + kc * 32 + lh * 8];
            a0 = __builtin_amdgcn_mfma_f32_16x16x32_bf16(a, b0, a0, 0, 0, 0);
            a1 = __builtin_amdgcn_mfma_f32_16x16x32_bf16(a, b1, a1, 0, 0, 0);
        }
        #pragma unroll
        for (int rg = 0; rg < 4; rg++) {
            bufE[(row0 + rg) * SA + wc + l15] = f2bf(a0[rg]);
            bufE[(row0 + rg) * SA + wc + 16 + l15] = f2bf(a1[rg]);
        }
    }
    __syncthreads();

    // ---- P10: GEMM1 Y = x0 @ w -> YT overlay in bufA ----
    const int cb8 = (w8 >> 2) * 8;
    {
        f4v acc[8];
        #pragma unroll
        for (int nt = 0; nt < 8; nt++) acc[nt] = (f4v){0.f, 0.f, 0.f, 0.f};
        const s8v* wf = (const s8v*)wfrag;
        #pragma unroll
        for (int kc = 0; kc < 8; kc++) {
            s8v a = *(const s8v*)&bufA[(wr + l15) * 264 + kc * 32 + lh * 8];
            #pragma unroll
            for (int nt = 0; nt < 8; nt++) {
                s8v bv = wf[(size_t)(kc * 16 + cb8 + nt) * 64 + lane];
                acc[nt] = __builtin_amdgcn_mfma_f32_16x16x32_bf16(a, bv, acc[nt], 0, 0, 0);
            }
        }
        __syncthreads();   // x0 dead -> YT overlay
        #pragma unroll
        for (int nt = 0; nt < 8; nt++) {
            int feat = (cb8 + nt) * 16 + l15;
            ushort4 u;
            u.x = f2bf(acc[nt][0]); u.y = f2bf(acc[nt][1]);
            u.z = f2bf(acc[nt][2]); u.w = f2bf(acc[nt][3]);
            *(ushort4*)&bufA[feat * SA + row0] = u;
        }
    }
    __syncthreads();

    // ---- P11: out = M @ Y + x0 ----
    {
        f4v acc2[8];
        #pragma unroll
        for (int nt = 0; nt < 8; nt++) acc2[nt] = (f4v){0.f, 0.f, 0.f, 0.f};
        #pragma unroll
        for (int kc = 0; kc < 2; kc++) {
            s8v a = *(const s8v*)&bufE[(wr + l15) * SA + kc * 32 + lh * 8];
            #pragma unroll
            for (int nt = 0; nt < 8; nt++) {
                s8v bv = *(const s8v*)&bufA[((cb8 + nt) * 16 + l15) * SA + kc * 32 + lh * 8];
                acc2[nt] = __builtin_amdgcn_mfma_f32_16x16x32_bf16(a, bv, acc2[nt], 0, 0, 0);
            }
        }
        #pragma unroll
        for (int nt = 0; nt < 8; nt++) {
            #pragma unroll
            for (int rg = 0; rg < 4; rg++) {
                int row = row0 + rg;
                int colg = (cb8 + nt) * 16 + l15;
                float r = emb_w[(size_t)idxs[row] * DD + colg];
                float v = acc2[nt][rg] + r;
                size_t o = (size_t)(b * 64 + row) * DD + colg;
                out[o] = v;
                out[BND + o] = v;
            }
        }
    }
}

extern "C" void kernel_launch(void* const* d_in, const int* in_sizes, int n_in,
                              void* d_out, int out_size, void* d_ws, size_t ws_size,
                              hipStream_t stream) {
    const int* inputs = (const int*)d_in[0];
    const int* HT = (const int*)d_in[1];
    const float* emb_w  = (const float*)d_in[4];
    const float* emb2_w = (const float*)d_in[5];
    const float* g1_w2 = (const float*)d_in[6];
    const float* g1_w3 = (const float*)d_in[7];
    const float* g1_a  = (const float*)d_in[8];
    const float* g1_a2 = (const float*)d_in[9];
    const float* g1_wc = (const float*)d_in[10];
    const float* g2_w  = (const float*)d_in[11];
    const float* g2_w2 = (const float*)d_in[12];
    const float* g2_w3 = (const float*)d_in[13];
    const float* g2_a  = (const float*)d_in[14];
    const float* g2_a2 = (const float*)d_in[15];
    const float* g2_wc = (const float*)d_in[16];

    float* out = (float*)d_out;
    float* prep = (float*)((char*)d_ws + WS_PREP);
    float* p3b_ws = (float*)((char*)d_ws + WS_P3B);
    unsigned short* wfrag = (unsigned short*)((char*)d_ws + WS_WFRAG);

    prep_dots<<<16, 256, 0, stream>>>(g1_w2, g1_w3, g1_a, g1_a2, g1_wc,
                                      g2_w2, g2_w3, g2_a, g2_a2, g2_wc,
                                      prep, p3b_ws);
    prep2_pack<<<40, 256, 0, stream>>>(g2_w, p3b_ws, prep, wfrag);
    mega<<<BB, 512, 0, stream>>>(inputs, HT, emb_w, emb2_w, prep, wfrag, out);
}

// Round 9
// 64.473 us; speedup vs baseline: 1.8656x; 1.3708x over previous
//
#include <hip/hip_runtime.h>

#define BB 512
#define NN 64
#define EE 64
#define DD 256
#define BND (BB * NN * DD)
#define SA 68

typedef __attribute__((ext_vector_type(8))) short s8v;
typedef __attribute__((ext_vector_type(4))) float f4v;
typedef __attribute__((ext_vector_type(8))) unsigned short u16x8;

__device__ __forceinline__ unsigned short f2bf(float f) {
    unsigned int x = __float_as_uint(f);
    x = x + 0x7fffu + ((x >> 16) & 1u);   // RNE
    return (unsigned short)(x >> 16);
}
__device__ __forceinline__ float lrelu(float v) { return v > 0.f ? v : 0.2f * v; }

// ws byte offsets
#define WS_PREP  0          // 2048 f32 (8KB)
#define WS_P3B   8192       // 256 f32
#define WS_WFRAG 12288      // 65536 bf16 (128KB)

// prep layout (floats): [0)p1a [256)p2a [512)p3a [768]c0a [1024)p1b [1280)p2b [1536)wp3b [1792]c0b
__global__ void prep_dots(const float* __restrict__ w2a, const float* __restrict__ w3a,
                          const float* __restrict__ aa, const float* __restrict__ a2a,
                          const float* __restrict__ wca,
                          const float* __restrict__ w2b, const float* __restrict__ w3b,
                          const float* __restrict__ ab, const float* __restrict__ a2b,
                          const float* __restrict__ wcb,
                          float* __restrict__ prep, float* __restrict__ p3b_ws) {
    const int t = threadIdx.x;
    const int blk = blockIdx.x;
    const int layer = blk >> 3;
    const int r0 = (blk & 7) * 32;
    __shared__ float vhi[256], v2lo[256], v2hi[256], red[256];
    const float* w2 = layer ? w2b : w2a;
    const float* w3 = layer ? w3b : w3a;
    const float* av = layer ? ab : aa;
    const float* a2 = layer ? a2b : a2a;
    vhi[t] = av[256 + t];
    v2lo[t] = a2[t];
    v2hi[t] = a2[256 + t];
    __syncthreads();
    const int row = r0 + (t >> 3), q = t & 7;
    const float* w2r = w2 + (size_t)row * DD + q * 32;
    const float* w3r = w3 + (size_t)row * DD + q * 32;
    float s1 = 0.f, s2 = 0.f, s3 = 0.f;
    #pragma unroll
    for (int c = 0; c < 8; c++) {
        float4 v = *(const float4*)&w2r[c * 4];
        float4 u = *(const float4*)&w3r[c * 4];
        float4 p1 = *(const float4*)&vhi[q * 32 + c * 4];
        float4 p2 = *(const float4*)&v2lo[q * 32 + c * 4];
        float4 p3 = *(const float4*)&v2hi[q * 32 + c * 4];
        s1 = fmaf(v.x, p1.x, fmaf(v.y, p1.y, fmaf(v.z, p1.z, fmaf(v.w, p1.w, s1))));
        s2 = fmaf(v.x, p2.x, fmaf(v.y, p2.y, fmaf(v.z, p2.z, fmaf(v.w, p2.w, s2))));
        s3 = fmaf(u.x, p3.x, fmaf(u.y, p3.y, fmaf(u.z, p3.z, fmaf(u.w, p3.w, s3))));
    }
    s1 += __shfl_xor(s1, 1); s1 += __shfl_xor(s1, 2); s1 += __shfl_xor(s1, 4);
    s2 += __shfl_xor(s2, 1); s2 += __shfl_xor(s2, 2); s2 += __shfl_xor(s2, 4);
    s3 += __shfl_xor(s3, 1); s3 += __shfl_xor(s3, 2); s3 += __shfl_xor(s3, 4);
    if (q == 0) {
        if (layer == 0) { prep[row] = s1; prep[256 + row] = s2; prep[512 + row] = s3; }
        else { prep[1024 + row] = s1; prep[1280 + row] = s2; p3b_ws[row] = s3; }
    }
    if ((blk & 7) == 0) {
        red[t] = layer ? (wcb[t] * ab[t]) : (wca[t] * aa[t]);
        __syncthreads();
        for (int o = 128; o > 0; o >>= 1) { if (t < o) red[t] += red[t + o]; __syncthreads(); }
        if (t == 0) prep[layer ? 1792 : 768] = red[0];
    }
}

// blocks 0..7: wp3b = wtr @ p3b ; blocks 8..39: pack g2_w into MFMA B-fragments
__global__ void prep2_pack(const float* __restrict__ wtr, const float* __restrict__ p3b_ws,
                           float* __restrict__ prep, unsigned short* __restrict__ wfrag) {
    const int t = threadIdx.x, blk = blockIdx.x;
    __shared__ float p3[256];
    if (blk < 8) {
        p3[t] = p3b_ws[t];
        __syncthreads();
        const int row = blk * 32 + (t >> 3), q = t & 7;
        const float* wr = wtr + (size_t)row * DD + q * 32;
        float s = 0.f;
        #pragma unroll
        for (int c = 0; c < 8; c++) {
            float4 v = *(const float4*)&wr[c * 4];
            float4 p = *(const float4*)&p3[q * 32 + c * 4];
            s = fmaf(v.x, p.x, fmaf(v.y, p.y, fmaf(v.z, p.z, fmaf(v.w, p.w, s))));
        }
        s += __shfl_xor(s, 1); s += __shfl_xor(s, 2); s += __shfl_xor(s, 4);
        if (q == 0) prep[1536 + row] = s;
    } else {
        int gid = (blk - 8) * 256 + t;      // 0..8191
        int l = gid & 63, frag = gid >> 6;
        int kc = frag >> 4, nt = frag & 15;
        int kb = kc * 32 + (l >> 4) * 8;
        int n = nt * 16 + (l & 15);
        u16x8 u;
        #pragma unroll
        for (int j = 0; j < 8; j++) u[j] = f2bf(wtr[(size_t)(kb + j) * DD + n]);
        *(u16x8*)(wfrag + (size_t)gid * 8) = u;
    }
}

// One block per batch. All reductions (softmax sums, dv dots, db2 matvec) via MFMA;
// softmax phases are select+store only (one global-max shfl chain per phase).
__launch_bounds__(512, 4)
__global__ void mega(const int* __restrict__ inputs, const int* __restrict__ HT,
                     const float* __restrict__ emb_w, const float* __restrict__ emb2_w,
                     const float* __restrict__ prep, const unsigned short* __restrict__ wfrag,
                     float* __restrict__ out) {
    __shared__ unsigned short bufA[256 * SA];  // x0bf [64][264] -> YT [256][68]
    __shared__ unsigned short RA[64 * SA];     // Pe1^T -> Pe2^T -> M(row)
    __shared__ unsigned short RB[64 * SA];     // Pn1'(row) -> Pn2'(row)
    __shared__ unsigned short RC[64 * SA];     // Pe1row -> C1'row -> Pe2row -> C2row
    __shared__ unsigned short RD[64 * SA];     // C1'^T [m][n]
    __shared__ unsigned short pvs[6 * 256];    // p-vectors bf16
    __shared__ unsigned short Debf[64];
    __shared__ float dvs[384];                 // j*64+n
    __shared__ float db2[192];
    __shared__ float u1f[64], invdef[64], invdnf[64];
    __shared__ unsigned long long mE[64], mN[64];
    __shared__ int idxs[64];

    const int b = blockIdx.x;
    const int t = threadIdx.x;
    const int lane = t & 63;
    const int w8 = t >> 6;
    const int l15 = lane & 15, lh = lane >> 4;

    // ---- P1: pvs bf16 stage; x0 stage; mE ballots; nodes2 copy; idxs ----
    if (t < 64) idxs[t] = inputs[b * 64 + t];
    for (int i = t; i < 1536; i += 512) {
        int off = i + (((i >> 8) >= 3) ? 256 : 0);
        pvs[i] = f2bf(prep[off]);
    }
    {
        const int rw = t >> 3, q8 = t & 7;
        const int idx = inputs[b * 64 + rw];
        const float* src = emb_w + (size_t)idx * DD + q8 * 32;
        #pragma unroll
        for (int c = 0; c < 8; c++) {
            float4 v = ((const float4*)src)[c];
            ushort4 u;
            u.x = f2bf(v.x); u.y = f2bf(v.y); u.z = f2bf(v.z); u.w = f2bf(v.w);
            *(ushort4*)&bufA[rw * 264 + q8 * 32 + c * 4] = u;
        }
    }
    #pragma unroll
    for (int i = 0; i < 8; i++) {
        int e = w8 * 8 + i;
        int hx = HT[((size_t)b * EE + e) * NN + lane];
        unsigned long long m = __ballot(hx > 0);
        if (lane == 0) mE[e] = m;
    }
    for (int i = t; i < 64 * 64; i += 512) {
        int n = i >> 6, c = i & 63;
        int idx = inputs[b * 64 + n];
        float4 v = ((const float4*)(emb2_w + (size_t)idx * DD))[c];
        ((float4*)(out + (size_t)2 * BND + (size_t)(b * 64 + n) * DD))[c] = v;
    }
    __syncthreads();

    // ---- P1b: dv = x0 @ pvecs via MFMA (waves 0-3) ; mN (wave 4) ----
    if (w8 < 4) {
        const int wtile = w8 * 16;
        const int j = (l15 < 6) ? l15 : 5;
        f4v acc = {0.f, 0.f, 0.f, 0.f};
        #pragma unroll
        for (int kc = 0; kc < 8; kc++) {
            s8v a = *(const s8v*)&bufA[(wtile + l15) * 264 + kc * 32 + lh * 8];
            s8v bv = *(const s8v*)&pvs[j * 256 + kc * 32 + lh * 8];
            acc = __builtin_amdgcn_mfma_f32_16x16x32_bf16(a, bv, acc, 0, 0, 0);
        }
        if (l15 < 6) {
            #pragma unroll
            for (int rg = 0; rg < 4; rg++)
                dvs[l15 * 64 + wtile + lh * 4 + rg] = acc[rg];
        }
    } else if (w8 == 4) {
        unsigned long long acc = 0ull;
        for (int e = 0; e < 64; e++) acc |= ((mE[e] >> lane) & 1ull) << e;
        mN[lane] = acc;
    }
    __syncthreads();

    const int wr = (w8 & 3) * 16;
    const int wc = (w8 >> 2) * 32;
    const int row0 = wr + lh * 4;

    // ================= layer 1 =================
    // ---- P2: Pe1 (global-shift exp, masked) -> RA (^T) + RC (row) ----
    {
        float s1l = lrelu(prep[768] + dvs[lane]);
        float g1 = s1l;
        #pragma unroll
        for (int o = 32; o > 0; o >>= 1) g1 = fmaxf(g1, __shfl_xor(g1, o));
        float E1 = __expf(s1l - g1);
        #pragma unroll
        for (int i = 0; i < 8; i++) {
            int e = w8 * 8 + i;
            unsigned long long me = mE[e];
            float pe = (me == 0ull) ? 1.f : (((me >> lane) & 1ull) ? E1 : 0.f);
            unsigned short bf = f2bf(pe);
            RA[lane * SA + e] = bf;
            RC[e * SA + lane] = bf;
        }
    }
    __syncthreads();

    // ---- P2b: [De;We] = [1;d2] x Pe (MFMA, waves 0-3) ----
    if (w8 < 4) {
        const int etile = w8 * 16;
        f4v acc = {0.f, 0.f, 0.f, 0.f};
        #pragma unroll
        for (int kc = 0; kc < 2; kc++) {
            u16x8 au;
            #pragma unroll
            for (int jj = 0; jj < 8; jj++) {
                float v = (l15 == 0) ? 1.f : ((l15 == 1) ? dvs[128 + kc * 32 + lh * 8 + jj] : 0.f);
                au[jj] = f2bf(v);
            }
            s8v bv = *(const s8v*)&RC[(etile + l15) * SA + kc * 32 + lh * 8];
            acc = __builtin_amdgcn_mfma_f32_16x16x32_bf16((s8v)au, bv, acc, 0, 0, 0);
        }
        if (lh == 0) {
            int e = etile + l15;
            float De = acc[0], We = acc[1];
            invdef[e] = 1.f / De;
            u1f[e] = We / De;
            Debf[e] = f2bf(De);
        }
    }
    __syncthreads();

    // ---- P3: Pn1' = Pn1 * (1/De) -> RB (row-major) ----
    {
        float t2l = dvs[64 + lane];
        float gt2 = t2l;
        #pragma unroll
        for (int o = 32; o > 0; o >>= 1) gt2 = fmaxf(gt2, __shfl_xor(gt2, o));
        float um = u1f[lane];
        #pragma unroll
        for (int o = 32; o > 0; o >>= 1) um = fmaxf(um, __shfl_xor(um, o));
        float M1 = lrelu(gt2 + um);
        float ul = u1f[lane];
        float ide = invdef[lane];
        #pragma unroll
        for (int i = 0; i < 8; i++) {
            int n = w8 * 8 + i;
            unsigned long long mn = mN[n];
            float t2n = dvs[64 + n];
            float pr = (mn == 0ull) ? 1.f
                     : (((mn >> lane) & 1ull) ? __expf(lrelu(t2n + ul) - M1) : 0.f);
            RB[n * SA + lane] = f2bf(pr * ide);
        }
    }
    __syncthreads();

    // ---- P3b: Dn1 = De . Pn1'^T (MFMA, waves 0-3) -> invdnf ----
    if (w8 < 4) {
        const int ntile = w8 * 16;
        f4v acc = {0.f, 0.f, 0.f, 0.f};
        #pragma unroll
        for (int kc = 0; kc < 2; kc++) {
            u16x8 au;
            #pragma unroll
            for (int jj = 0; jj < 8; jj++) au[jj] = Debf[kc * 32 + lh * 8 + jj];
            s8v bv = *(const s8v*)&RB[(ntile + l15) * SA + kc * 32 + lh * 8];
            acc = __builtin_amdgcn_mfma_f32_16x16x32_bf16((s8v)au, bv, acc, 0, 0, 0);
        }
        if (lh == 0) invdnf[ntile + l15] = 1.f / acc[0];
    }
    __syncthreads();

    // ---- P4: C1' = Dn^-1 (Pn1' @ Pe1) + I -> RD [m][n] + RC [n][m] ----
    {
        f4v a0 = {0.f,0.f,0.f,0.f}, a1 = {0.f,0.f,0.f,0.f};
        #pragma unroll
        for (int kc = 0; kc < 2; kc++) {
            s8v a  = *(const s8v*)&RB[(wr + l15) * SA + kc * 32 + lh * 8];
            s8v b0 = *(const s8v*)&RA[(wc + l15) * SA + kc * 32 + lh * 8];
            s8v b1 = *(const s8v*)&RA[(wc + 16 + l15) * SA + kc * 32 + lh * 8];
            a0 = __builtin_amdgcn_mfma_f32_16x16x32_bf16(a, b0, a0, 0, 0, 0);
            a1 = __builtin_amdgcn_mfma_f32_16x16x32_bf16(a, b1, a1, 0, 0, 0);
        }
        int col0 = wc + l15, col1 = wc + 16 + l15;
        ushort4 u0, u1;
        #pragma unroll
        for (int rg = 0; rg < 4; rg++) {
            float idn = invdnf[row0 + rg];
            unsigned short b0s = f2bf(a0[rg] * idn + ((row0 + rg) == col0 ? 1.f : 0.f));
            unsigned short b1s = f2bf(a1[rg] * idn + ((row0 + rg) == col1 ? 1.f : 0.f));
            ((unsigned short*)&u0)[rg] = b0s;
            ((unsigned short*)&u1)[rg] = b1s;
            RC[(row0 + rg) * SA + col0] = b0s;
            RC[(row0 + rg) * SA + col1] = b1s;
        }
        *(ushort4*)&RD[col0 * SA + row0] = u0;
        *(ushort4*)&RD[col1 * SA + row0] = u1;
    }
    __syncthreads();

    // ---- P5: db2[j] = C1' @ dv[3+j] (MFMA on RC row-major, waves 0-3) ----
    if (w8 < 4) {
        const int ntile = w8 * 16;
        f4v acc = {0.f, 0.f, 0.f, 0.f};
        #pragma unroll
        for (int kc = 0; kc < 2; kc++) {
            u16x8 au;
            #pragma unroll
            for (int jj = 0; jj < 8; jj++) {
                float v = (l15 < 3) ? dvs[192 + l15 * 64 + kc * 32 + lh * 8 + jj] : 0.f;
                au[jj] = f2bf(v);
            }
            s8v bv = *(const s8v*)&RC[(ntile + l15) * SA + kc * 32 + lh * 8];
            acc = __builtin_amdgcn_mfma_f32_16x16x32_bf16((s8v)au, bv, acc, 0, 0, 0);
        }
        if (lh == 0) {
            int n = ntile + l15;
            db2[n] = acc[0]; db2[64 + n] = acc[1]; db2[128 + n] = acc[2];
        }
    }
    __syncthreads();

    // ================= layer 2 =================
    // ---- P6: Pe2 -> RA (^T) + RC (row) ----
    {
        float s2l = lrelu(prep[1792] + db2[lane]);
        float g2 = s2l;
        #pragma unroll
        for (int o = 32; o > 0; o >>= 1) g2 = fmaxf(g2, __shfl_xor(g2, o));
        float E2 = __expf(s2l - g2);
        #pragma unroll
        for (int i = 0; i < 8; i++) {
            int e = w8 * 8 + i;
            unsigned long long me = mE[e];
            float pe = (me == 0ull) ? 1.f : (((me >> lane) & 1ull) ? E2 : 0.f);
            unsigned short bf = f2bf(pe);
            RA[lane * SA + e] = bf;
            RC[e * SA + lane] = bf;
        }
    }
    __syncthreads();

    // ---- P6b: [De2;We2] via MFMA ----
    if (w8 < 4) {
        const int etile = w8 * 16;
        f4v acc = {0.f, 0.f, 0.f, 0.f};
        #pragma unroll
        for (int kc = 0; kc < 2; kc++) {
            u16x8 au;
            #pragma unroll
            for (int jj = 0; jj < 8; jj++) {
                float v = (l15 == 0) ? 1.f : ((l15 == 1) ? db2[128 + kc * 32 + lh * 8 + jj] : 0.f);
                au[jj] = f2bf(v);
            }
            s8v bv = *(const s8v*)&RC[(etile + l15) * SA + kc * 32 + lh * 8];
            acc = __builtin_amdgcn_mfma_f32_16x16x32_bf16((s8v)au, bv, acc, 0, 0, 0);
        }
        if (lh == 0) {
            int e = etile + l15;
            float De = acc[0], We = acc[1];
            invdef[e] = 1.f / De;
            u1f[e] = We / De;
            Debf[e] = f2bf(De);
        }
    }
    __syncthreads();

    // ---- P7: Pn2' -> RB ----
    {
        float d1l = db2[64 + lane];
        float gd1 = d1l;
        #pragma unroll
        for (int o = 32; o > 0; o >>= 1) gd1 = fmaxf(gd1, __shfl_xor(gd1, o));
        float um = u1f[lane];
        #pragma unroll
        for (int o = 32; o > 0; o >>= 1) um = fmaxf(um, __shfl_xor(um, o));
        float M2 = lrelu(gd1 + um);
        float ul = u1f[lane];
        float ide = invdef[lane];
        #pragma unroll
        for (int i = 0; i < 8; i++) {
            int n = w8 * 8 + i;
            unsigned long long mn = mN[n];
            float d1n = db2[64 + n];
            float pr = (mn == 0ull) ? 1.f
                     : (((mn >> lane) & 1ull) ? __expf(lrelu(d1n + ul) - M2) : 0.f);
            RB[n * SA + lane] = f2bf(pr * ide);
        }
    }
    __syncthreads();

    // ---- P7b: Dn2 via MFMA -> invdnf ----
    if (w8 < 4) {
        const int ntile = w8 * 16;
        f4v acc = {0.f, 0.f, 0.f, 0.f};
        #pragma unroll
        for (int kc = 0; kc < 2; kc++) {
            u16x8 au;
            #pragma unroll
            for (int jj = 0; jj < 8; jj++) au[jj] = Debf[kc * 32 + lh * 8 + jj];
            s8v bv = *(const s8v*)&RB[(ntile + l15) * SA + kc * 32 + lh * 8];
            acc = __builtin_amdgcn_mfma_f32_16x16x32_bf16((s8v)au, bv, acc, 0, 0, 0);
        }
        if (lh == 0) invdnf[ntile + l15] = 1.f / acc[0];
    }
    __syncthreads();

    // ---- P8: C2 = Dn2^-1 (Pn2' @ Pe2) -> RC (row-major) ----
    {
        f4v a0 = {0.f,0.f,0.f,0.f}, a1 = {0.f,0.f,0.f,0.f};
        #pragma unroll
        for (int kc = 0; kc < 2; kc++) {
            s8v a  = *(const s8v*)&RB[(wr + l15) * SA + kc * 32 + lh * 8];
            s8v b0 = *(const s8v*)&RA[(wc + l15) * SA + kc * 32 + lh * 8];
            s8v b1 = *(const s8v*)&RA[(wc + 16 + l15) * SA + kc * 32 + lh * 8];
            a0 = __builtin_amdgcn_mfma_f32_16x16x32_bf16(a, b0, a0, 0, 0, 0);
            a1 = __builtin_amdgcn_mfma_f32_16x16x32_bf16(a, b1, a1, 0, 0, 0);
        }
        __syncthreads();   // RC (Pe2row) reads in P6b done; safe to overwrite
        #pragma unroll
        for (int rg = 0; rg < 4; rg++) {
            float idn = invdnf[row0 + rg];
            RC[(row0 + rg) * SA + wc + l15] = f2bf(a0[rg] * idn);
            RC[(row0 + rg) * SA + wc + 16 + l15] = f2bf(a1[rg] * idn);
        }
    }
    __syncthreads();

    // ---- P9: M = C2 @ C1' -> RA (row-major; Pe2^T dead) ----
    {
        f4v a0 = {0.f,0.f,0.f,0.f}, a1 = {0.f,0.f,0.f,0.f};
        #pragma unroll
        for (int kc = 0; kc < 2; kc++) {
            s8v a  = *(const s8v*)&RC[(wr + l15) * SA + kc * 32 + lh * 8];
            s8v b0 = *(const s8v*)&RD[(wc + l15) * SA + kc * 32 + lh * 8];
            s8v b1 = *(const s8v*)&RD[(wc + 16 + l15) * SA + kc * 32 + lh * 8];
            a0 = __builtin_amdgcn_mfma_f32_16x16x32_bf16(a, b0, a0, 0, 0, 0);
            a1 = __builtin_amdgcn_mfma_f32_16x16x32_bf16(a, b1, a1, 0, 0, 0);
        }
        __syncthreads();   // RA reads in P8 done
        #pragma unroll
        for (int rg = 0; rg < 4; rg++) {
            RA[(row0 + rg) * SA + wc + l15] = f2bf(a0[rg]);
            RA[(row0 + rg) * SA + wc + 16 + l15] = f2bf(a1[rg]);
        }
    }
    __syncthreads();

    // ---- P10: GEMM1 Y = x0 @ w -> YT overlay in bufA ----
    const int cb8 = (w8 >> 2) * 8;
    {
        f4v acc[8];
        #pragma unroll
        for (int nt = 0; nt < 8; nt++) acc[nt] = (f4v){0.f, 0.f, 0.f, 0.f};
        const s8v* wf = (const s8v*)wfrag;
        #pragma unroll
        for (int kc = 0; kc < 8; kc++) {
            s8v a = *(const s8v*)&bufA[(wr + l15) * 264 + kc * 32 + lh * 8];
            #pragma unroll
            for (int nt = 0; nt < 8; nt++) {
                s8v bv = wf[(size_t)(kc * 16 + cb8 + nt) * 64 + lane];
                acc[nt] = __builtin_amdgcn_mfma_f32_16x16x32_bf16(a, bv, acc[nt], 0, 0, 0);
            }
        }
        __syncthreads();   // x0 dead -> YT overlay
        #pragma unroll
        for (int nt = 0; nt < 8; nt++) {
            int feat = (cb8 + nt) * 16 + l15;
            ushort4 u;
            u.x = f2bf(acc[nt][0]); u.y = f2bf(acc[nt][1]);
            u.z = f2bf(acc[nt][2]); u.w = f2bf(acc[nt][3]);
            *(ushort4*)&bufA[feat * SA + row0] = u;
        }
    }
    __syncthreads();

    // ---- P11: out = M @ Y + x0 ----
    {
        f4v acc2[8];
        #pragma unroll
        for (int nt = 0; nt < 8; nt++) acc2[nt] = (f4v){0.f, 0.f, 0.f, 0.f};
        #pragma unroll
        for (int kc = 0; kc < 2; kc++) {
            s8v a = *(const s8v*)&RA[(wr + l15) * SA + kc * 32 + lh * 8];
            #pragma unroll
            for (int nt = 0; nt < 8; nt++) {
                s8v bv = *(const s8v*)&bufA[((cb8 + nt) * 16 + l15) * SA + kc * 32 + lh * 8];
                acc2[nt] = __builtin_amdgcn_mfma_f32_16x16x32_bf16(a, bv, acc2[nt], 0, 0, 0);
            }
        }
        #pragma unroll
        for (int nt = 0; nt < 8; nt++) {
            #pragma unroll
            for (int rg = 0; rg < 4; rg++) {
                int row = row0 + rg;
                int colg = (cb8 + nt) * 16 + l15;
                float r = emb_w[(size_t)idxs[row] * DD + colg];
                float v = acc2[nt][rg] + r;
                size_t o = (size_t)(b * 64 + row) * DD + colg;
                out[o] = v;
                out[BND + o] = v;
            }
        }
    }
}

extern "C" void kernel_launch(void* const* d_in, const int* in_sizes, int n_in,
                              void* d_out, int out_size, void* d_ws, size_t ws_size,
                              hipStream_t stream) {
    const int* inputs = (const int*)d_in[0];
    const int* HT = (const int*)d_in[1];
    const float* emb_w  = (const float*)d_in[4];
    const float* emb2_w = (const float*)d_in[5];
    const float* g1_w2 = (const float*)d_in[6];
    const float* g1_w3 = (const float*)d_in[7];
    const float* g1_a  = (const float*)d_in[8];
    const float* g1_a2 = (const float*)d_in[9];
    const float* g1_wc = (const float*)d_in[10];
    const float* g2_w  = (const float*)d_in[11];
    const float* g2_w2 = (const float*)d_in[12];
    const float* g2_w3 = (const float*)d_in[13];
    const float* g2_a  = (const float*)d_in[14];
    const float* g2_a2 = (const float*)d_in[15];
    const float* g2_wc = (const float*)d_in[16];

    float* out = (float*)d_out;
    float* prep = (float*)((char*)d_ws + WS_PREP);
    float* p3b_ws = (float*)((char*)d_ws + WS_P3B);
    unsigned short* wfrag = (unsigned short*)((char*)d_ws + WS_WFRAG);

    prep_dots<<<16, 256, 0, stream>>>(g1_w2, g1_w3, g1_a, g1_a2, g1_wc,
                                      g2_w2, g2_w3, g2_a, g2_a2, g2_wc,
                                      prep, p3b_ws);
    prep2_pack<<<40, 256, 0, stream>>>(g2_w, p3b_ws, prep, wfrag);
    mega<<<BB, 512, 0, stream>>>(inputs, HT, emb_w, emb2_w, prep, wfrag, out);
}